// Round 2
// baseline (333.795 us; speedup 1.0000x reference)
//
#include <hip/hip_runtime.h>

#define EPSF  1e-8f
#define IMG_W 512
#define IMG_H 512
#define HWPX  (IMG_W*IMG_H)
#define NB    32

// ws layout: minb[NB] | maxb[NB] | sdsum[NB] | cand[3*NB]
// cand[0*NB+b] : sum of m1^0.2 * m2^0.8   (case mean_SD in (0.85, 1])
// cand[1*NB+b] : sum of m1^0.8 * m2^0.2   (case mean_SD in [0, 0.85])
// cand[2*NB+b] : sum of sqrt(m1*m2)       (else)

// ---------------- init: reset accumulators in ws ----------------
__global__ void k_init(unsigned* __restrict__ minb, unsigned* __restrict__ maxb,
                       float* __restrict__ sdsum, float* __restrict__ cand) {
  int t = threadIdx.x;
  if (t < NB) { minb[t] = 0x7F7FFFFFu; /*FLT_MAX bits*/ maxb[t] = 0u; sdsum[t] = 0.f; }
  if (t < 3*NB) cand[t] = 0.f;
}

// ---------------- pass 1: per-sample min/max of grayscale(D) ----------------
__global__ __launch_bounds__(256) void k_minmax(const float* __restrict__ D,
                                                unsigned* __restrict__ minb,
                                                unsigned* __restrict__ maxb) {
  const int b = blockIdx.y, chunk = blockIdx.x, tid = threadIdx.x;
  const float4* P0 = (const float4*)(D + (size_t)b * 3 * HWPX);
  const float4* P1 = P0 + HWPX/4;
  const float4* P2 = P1 + HWPX/4;
  float mn = __uint_as_float(0x7F7FFFFFu), mx = 0.f;   // Dg >= 0 always
  const int base = chunk * 2048;
  #pragma unroll
  for (int it = 0; it < 8; ++it) {
    int i = base + it*256 + tid;
    float4 a = P0[i], c = P1[i], e = P2[i];
    float g;
    g = 0.2989f*a.x + 0.587f*c.x + 0.114f*e.x; mn = fminf(mn,g); mx = fmaxf(mx,g);
    g = 0.2989f*a.y + 0.587f*c.y + 0.114f*e.y; mn = fminf(mn,g); mx = fmaxf(mx,g);
    g = 0.2989f*a.z + 0.587f*c.z + 0.114f*e.z; mn = fminf(mn,g); mx = fmaxf(mx,g);
    g = 0.2989f*a.w + 0.587f*c.w + 0.114f*e.w; mn = fminf(mn,g); mx = fmaxf(mx,g);
  }
  #pragma unroll
  for (int o = 32; o > 0; o >>= 1) {
    mn = fminf(mn, __shfl_down(mn, o, 64));
    mx = fmaxf(mx, __shfl_down(mx, o, 64));
  }
  __shared__ float smn[4], smx[4];
  if ((tid & 63) == 0) { smn[tid>>6] = mn; smx[tid>>6] = mx; }
  __syncthreads();
  if (tid == 0) {
    mn = fminf(fminf(smn[0],smn[1]), fminf(smn[2],smn[3]));
    mx = fmaxf(fmaxf(smx[0],smx[1]), fmaxf(smx[2],smx[3]));
    // non-negative floats order identically as uints
    atomicMin(minb + b, __float_as_uint(mn));
    atomicMax(maxb + b, __float_as_uint(mx));
  }
}

// ---------------- pass 2: fused MSCN + Sobel + maps; 3 candidate sums + SD sum ----------------
#define TW 64
#define TH 32
#define HALO 3
#define SW (TW+2*HALO)   // 70
#define SH (TH+2*HALO)   // 38

__global__ __launch_bounds__(256) void k_main(const float* __restrict__ D, const float* __restrict__ R,
                                              const unsigned* __restrict__ minb,
                                              const unsigned* __restrict__ maxb,
                                              float* __restrict__ sdsum,
                                              float* __restrict__ cand) {
  __shared__ float sDg[SH][SW];
  __shared__ float sRg[SH][SW];
  __shared__ float sSD[TH][TW];
  __shared__ float sSC[TH][TW];

  const int tid = threadIdx.x;
  const int b   = blockIdx.z;
  const int tx0 = blockIdx.x * TW;
  const int ty0 = blockIdx.y * TH;

  // per-sample constants (broadcast loads, L2-hot)
  const float dr = __uint_as_float(maxb[b]) - __uint_as_float(minb[b]);
  const float CM = (0.01f*dr)*(0.01f*dr);
  const float CD = 0.5f*CM;
  const float CG = (0.03f*dr)*(0.03f*dr);
  const float CC = 0.5f*CG;

  const float* D0 = D + (size_t)b*3*HWPX;
  const float* D1 = D0 + HWPX;
  const float* D2 = D1 + HWPX;
  const float* R0 = R + (size_t)b*3*HWPX;
  const float* R1 = R0 + HWPX;
  const float* R2 = R1 + HWPX;

  float sdacc = 0.f;

  // ---- stage: grayscale tile (with halo, zero-padded) + SD/SC maps for center ----
  for (int i = tid; i < SH*SW; i += 256) {
    int r = i / SW, c = i % SW;
    int gy = ty0 - HALO + r, gx = tx0 - HALO + c;
    float dg = 0.f, rg = 0.f;
    if ((unsigned)gy < IMG_H && (unsigned)gx < IMG_W) {
      size_t off = (size_t)gy*IMG_W + gx;
      float d0=D0[off], d1=D1[off], d2=D2[off];
      float r0=R0[off], r1=R1[off], r2=R2[off];
      dg = 0.2989f*d0 + 0.587f*d1 + 0.114f*d2;
      rg = 0.2989f*r0 + 0.587f*r1 + 0.114f*r2;
      if (r >= HALO && r < HALO+TH && c >= HALO && c < HALO+TW) {
        float dmn = fminf(fminf(d0,d1),d2);
        float rmn = fminf(fminf(r0,r1),r2);
        float a_ = dmn*(1.f/255.f), c_ = rmn*(1.f/255.f);
        float sd = (2.f*a_*c_ + CD)/(a_*a_ + c_*c_ + CD + EPSF);
        sSD[r-HALO][c-HALO] = sd;
        sdacc += sd;
        float dmx = fmaxf(fmaxf(d0,d1),d2);
        float rmx = fmaxf(fmaxf(r0,r1),r2);
        float dcol = ((dmx-dmn+EPSF)/(dmx+EPSF))*dmx;
        float rcol = ((rmx-rmn+EPSF)/(rmx+EPSF))*rmx;
        sSC[r-HALO][c-HALO] = (2.f*dcol*rcol + CC)/(dcol*dcol + rcol*rcol + CC + EPSF);
      }
    }
    sDg[r][c] = dg;
    sRg[r][c] = rg;
  }
  __syncthreads();

  // gaussian weights (matches np: exp(-0.5*(x/(7/6))^2), normalized)
  float gw[7];
  {
    float sum = 0.f;
    #pragma unroll
    for (int j = 0; j < 7; ++j) {
      float t = (float)(j-3) * (6.f/7.f);
      float v = expf(-0.5f * t * t);
      gw[j] = v; sum += v;
    }
    float inv = 1.f/sum;
    #pragma unroll
    for (int j = 0; j < 7; ++j) gw[j] *= inv;
  }

  // ---- separable conv with per-column rolling window of horizontal partials ----
  const int x   = tid & 63;         // column within tile
  const int yo0 = (tid >> 6) * 8;   // 4 row-groups x 8 output rows

  float whgD[7], whqD[7], whgR[7], whqR[7];   // gauss partials (g, g^2)
  float wsxD[7], wsyD[7], wsxR[7], wsyR[7];   // sobel row partials
  float a0 = 0.f, a1 = 0.f, a2 = 0.f;

  #pragma unroll
  for (int step = 0; step < 14; ++step) {
    const int r = yo0 + step;       // LDS row (gy = ty0 - 3 + r)
    float vD[7], vR[7];
    #pragma unroll
    for (int j = 0; j < 7; ++j) { vD[j] = sDg[r][x+j]; vR[j] = sRg[r][x+j]; }
    float hgD=0.f, hqD=0.f, hgR=0.f, hqR=0.f;
    #pragma unroll
    for (int j = 0; j < 7; ++j) {
      hgD += gw[j]*vD[j]; hqD += gw[j]*vD[j]*vD[j];
      hgR += gw[j]*vR[j]; hqR += gw[j]*vR[j]*vR[j];
    }
    float sxD = vD[2]-vD[4], syD = vD[2]+2.f*vD[3]+vD[4];
    float sxR = vR[2]-vR[4], syR = vR[2]+2.f*vR[3]+vR[4];
    #pragma unroll
    for (int j = 0; j < 6; ++j) {
      whgD[j]=whgD[j+1]; whqD[j]=whqD[j+1]; whgR[j]=whgR[j+1]; whqR[j]=whqR[j+1];
      wsxD[j]=wsxD[j+1]; wsyD[j]=wsyD[j+1]; wsxR[j]=wsxR[j+1]; wsyR[j]=wsyR[j+1];
    }
    whgD[6]=hgD; whqD[6]=hqD; whgR[6]=hgR; whqR[6]=hqR;
    wsxD[6]=sxD; wsyD[6]=syD; wsxR[6]=sxR; wsyR[6]=syR;

    if (step >= 6) {
      const int yo = yo0 + step - 6;   // output row; window w[j] holds h-row yo+j (LDS idx)
      float muD=0.f, exD=0.f, muR=0.f, exR=0.f;
      #pragma unroll
      for (int j = 0; j < 7; ++j) {
        muD += gw[j]*whgD[j]; exD += gw[j]*whqD[j];
        muR += gw[j]*whgR[j]; exR += gw[j]*whqR[j];
      }
      float v0D = sDg[yo+HALO][x+HALO];
      float v0R = sRg[yo+HALO][x+HALO];
      float sigD = sqrtf(fabsf(exD - muD*muD + EPSF));
      float sigR = sqrtf(fabsf(exR - muR*muR + EPSF));
      float Dm = (v0D - muD) / (sigD + EPSF);
      float Rm = (v0R - muR) / (sigR + EPSF);
      float SM = (2.f*Dm*Rm + CM) / (Dm*Dm + Rm*Rm + CM);
      // sobel rows offset -1,0,+1 -> window idx 2,3,4
      float gxD = wsxD[2] + 2.f*wsxD[3] + wsxD[4];
      float gyD = wsyD[2] - wsyD[4];
      float gxR = wsxR[2] + 2.f*wsxR[3] + wsxR[4];
      float gyR = wsyR[2] - wsyR[4];
      float GD = sqrtf(gxD*gxD + gyD*gyD + EPSF);
      float GR = sqrtf(gxR*gxR + gyR*gyR + EPSF);
      float SG = (2.f*GD*GR + CG) / (GD*GD + GR*GR + CG + EPSF);
      float SDv = sSD[yo][x];
      float SCv = sSC[yo][x];
      float m1 = fabsf(SM * SDv);
      float m2 = SG * SCv;               // strictly positive
      float l1 = log2f(m1);              // m1==0 -> -inf -> exp2 -> 0, correct
      float l2 = log2f(m2);
      a0 += exp2f(0.2f*l1 + 0.8f*l2);
      a1 += exp2f(0.8f*l1 + 0.2f*l2);
      a2 += exp2f(0.5f*l1 + 0.5f*l2);
    }
  }

  // ---- block-reduce 4 accumulators, one atomic each ----
  #pragma unroll
  for (int o = 32; o > 0; o >>= 1) {
    sdacc += __shfl_down(sdacc, o, 64);
    a0    += __shfl_down(a0,    o, 64);
    a1    += __shfl_down(a1,    o, 64);
    a2    += __shfl_down(a2,    o, 64);
  }
  __shared__ float red[4][4];
  const int w = tid >> 6;
  if ((tid & 63) == 0) { red[w][0]=sdacc; red[w][1]=a0; red[w][2]=a1; red[w][3]=a2; }
  __syncthreads();
  if (tid < 4) {
    float t = red[0][tid]+red[1][tid]+red[2][tid]+red[3][tid];
    if (tid == 0) atomicAdd(sdsum + b, t);
    else          atomicAdd(cand + (tid-1)*NB + b, t);
  }
}

// ---------------- pass 3: select candidate per sample, batch mean ----------------
__global__ void k_final(const float* __restrict__ sdsum, const float* __restrict__ cand,
                        float* __restrict__ out) {
  const int t = threadIdx.x;
  float v = 0.f;
  if (t < NB) {
    float meanSD = sdsum[t] * (1.f/(float)HWPX);
    float c;
    if      (meanSD > 0.85f && meanSD <= 1.0f)  c = cand[0*NB + t];
    else if (meanSD >= 0.f  && meanSD <= 0.85f) c = cand[1*NB + t];
    else                                        c = cand[2*NB + t];
    v = c;
  }
  #pragma unroll
  for (int o = 32; o > 0; o >>= 1) v += __shfl_down(v, o, 64);
  if (t == 0) out[0] = v * (1.f/8388608.f);   // 1/(H*W*B) = 2^-23 exact
}

extern "C" void kernel_launch(void* const* d_in, const int* in_sizes, int n_in,
                              void* d_out, int out_size, void* d_ws, size_t ws_size,
                              hipStream_t stream) {
  (void)in_sizes; (void)n_in; (void)out_size; (void)ws_size;
  const float* D = (const float*)d_in[0];
  const float* R = (const float*)d_in[1];
  float* out = (float*)d_out;
  unsigned* minb  = (unsigned*)d_ws;
  unsigned* maxb  = minb + NB;
  float*    sdsum = (float*)(maxb + NB);
  float*    cand  = sdsum + NB;

  k_init  <<<1, 128, 0, stream>>>(minb, maxb, sdsum, cand);
  k_minmax<<<dim3(32, NB), 256, 0, stream>>>(D, minb, maxb);
  k_main  <<<dim3(IMG_W/TW, IMG_H/TH, NB), 256, 0, stream>>>(D, R, minb, maxb, sdsum, cand);
  k_final <<<1, 64, 0, stream>>>(sdsum, cand, out);
}